// Round 3
// baseline (273.374 us; speedup 1.0000x reference)
//
#include <hip/hip_runtime.h>
#include <hip/hip_bf16.h>

typedef unsigned short u16;
typedef __attribute__((ext_vector_type(8))) short short8;
typedef __attribute__((ext_vector_type(4))) float floatx4;

// ---- problem constants ----
#define BB 64
#define SS 192
#define DD 768
#define HH 3072
#define EE 6
#define PP 256
#define SHARED_N 512
#define M_TOT (BB * SS)          // 12288

#define GLD16(gp, lp) __builtin_amdgcn_global_load_lds(                         \
    (const __attribute__((address_space(1))) unsigned int*)(gp),                \
    (__attribute__((address_space(3))) unsigned int*)(lp), 16, 0, 0)

__device__ __forceinline__ u16 f2b(float x) {
  union { float f; unsigned u; } c; c.f = x;
  return (u16)((c.u + 0x7fffu + ((c.u >> 16) & 1u)) >> 16);  // RTNE
}

// tanh-form GELU via sigmoid identity: 0.5x(1+tanh(z)) == x*sigmoid(2z).
__device__ __forceinline__ float fast_gelu(float x) {
  const float c = 2.0f * 0.7978845608028654f * 1.4426950408889634f; // 2*sqrt(2/pi)*log2(e)
  float xp = __builtin_fmaf(0.044715f * x * x, x, x);
  float e = __builtin_amdgcn_exp2f(-c * xp);
  return x * __builtin_amdgcn_rcpf(1.0f + e);
}

// -------- fp32 -> bf16 conversion, all 4 operands in ONE launch --------
#define N_X  9437184L   // 12288*768
#define N_W1 2359296L   // 3072*768
#define N_W2 1572864L   // 512*3072
#define N_WE 4718592L   // 6*256*3072
#define N_ALL (N_X + N_W1 + N_W2 + N_WE)  // 18087936

__global__ __launch_bounds__(256) void cvt_all_kernel(const float* __restrict__ x,
                                                      const float* __restrict__ w1,
                                                      const float* __restrict__ w2,
                                                      const float* __restrict__ we,
                                                      u16* __restrict__ dst) {
  long i = ((long)blockIdx.x * blockDim.x + threadIdx.x) * 8;
  const float* src;
  if (i < N_X)                  src = x  + i;
  else if (i < N_X + N_W1)      src = w1 + (i - N_X);
  else if (i < N_X + N_W1 + N_W2) src = w2 + (i - N_X - N_W1);
  else                          src = we + (i - N_X - N_W1 - N_W2);
  float4 a = *(const float4*)(src);
  float4 b = *(const float4*)(src + 4);
  union { u16 us[8]; uint4 v; } r;
  r.us[0] = f2b(a.x); r.us[1] = f2b(a.y); r.us[2] = f2b(a.z); r.us[3] = f2b(a.w);
  r.us[4] = f2b(b.x); r.us[5] = f2b(b.y); r.us[6] = f2b(b.z); r.us[7] = f2b(b.w);
  *(uint4*)(dst + i) = r.v;
}

// ---------------- GEMM1: h = gelu(X @ W1^T + b1), bf16 out ----------------
// Counted-vmcnt phased schedule (T3+T4+T5) with TRIPLE-buffered LDS.
// BM=256, BN=128, BK=64; 512 threads = 8 waves (4M x 2N), 64x64 output/wave.
// 3 LDS slots (3 x 48KB = 144KB): tile t+2 is staged into tile t-1's slot,
// which was fully consumed last iteration -> no WAR hazard -> the
// global_load_lds queue NEVER drains in the main loop (vmcnt(6), not 0).
// Per K-tile: 2 phases of {8 ds_read_b128 | 3 GLD16 | s_barrier | lgkmcnt(0) |
// setprio(1) 16 MFMA setprio(0) | s_barrier}; one vmcnt(6) per K-tile.
// R3 FIX: epilogue store loop geometry was still 128x128 (covered only cols
// 0..63 of the 128-wide tile -> half of H stale -> absmax 1.4). Now 4096
// chunks = 256 rows x 16 chunks, 8 iters of 512.
#define NT1 12            // K/64
#define EPI_STRIDE 136    // 272B row stride: 16B-aligned rows, 4-bank rotation
__global__ __launch_bounds__(512, 2) void gemm1_kernel(const u16* __restrict__ X,
                                                       const u16* __restrict__ W,
                                                       const float* __restrict__ bias,
                                                       u16* __restrict__ H) {
  constexpr int K = DD;      // 768
  constexpr int N = HH;      // 3072
  // slots: A[s] = smem + s*16384 (256x64), B[s] = smem + 49152 + s*8192 (128x64)
  __shared__ u16 smem[3 * 16384 + 3 * 8192];   // 147456 B
  const int tid = threadIdx.x;
  const int lane = tid & 63;
  const int wave = tid >> 6;
  const int m0 = blockIdx.x * 256;
  const int n0 = blockIdx.y * 128;
  const int wm = (wave >> 1) * 64;   // 0,64,128,192
  const int wn = (wave & 1) * 64;    // 0,64
  const int q = lane >> 4;
  const int r = lane & 15;
  const int xr = r & 7;

  // staging assignments (chunk = 16B = 8 bf16). LDS dest is LINEAR (GLD16
  // requires it); the XOR swizzle is applied to the GLOBAL source chunk, and
  // un-applied on the ds_read side (both-sides rule, guide G21).
  const u16* a_src[4]; int a_dst[4];
#pragma unroll
  for (int i = 0; i < 4; ++i) {
    const int c = i * 512 + tid;        // 0..2047
    const int row = c >> 3;             // 0..255
    const int g = (c & 7) ^ (row & 7);
    a_src[i] = X + (long)(m0 + row) * K + g * 8;
    a_dst[i] = c * 8;
  }
  const u16* b_src[2]; int b_dst[2];
#pragma unroll
  for (int i = 0; i < 2; ++i) {
    const int c = i * 512 + tid;        // 0..1023
    const int row = c >> 3;             // 0..127
    const int g = (c & 7) ^ (row & 7);
    b_src[i] = W + (long)(n0 + row) * K + g * 8;
    b_dst[i] = c * 8;
  }

  floatx4 acc[4][4] = {};

  // ---- prologue: stage tile 0 -> slot 0, tile 1 -> slot 1 (12 loads) ----
#pragma unroll
  for (int i = 0; i < 4; ++i) GLD16(a_src[i], smem + a_dst[i]);
#pragma unroll
  for (int i = 0; i < 2; ++i) GLD16(b_src[i], smem + 49152 + b_dst[i]);
#pragma unroll
  for (int i = 0; i < 4; ++i) GLD16(a_src[i] + 64, smem + 16384 + a_dst[i]);
#pragma unroll
  for (int i = 0; i < 2; ++i) GLD16(b_src[i] + 64, smem + 49152 + 8192 + b_dst[i]);
  asm volatile("s_waitcnt vmcnt(6)" ::: "memory");   // tile 0 fully landed
  __builtin_amdgcn_sched_barrier(0);
  __builtin_amdgcn_s_barrier();

#pragma unroll
  for (int kt = 0; kt < NT1; ++kt) {
    u16* As = smem + (kt % 3) * 16384;
    u16* Bs = smem + 49152 + (kt % 3) * 8192;
    const int s2 = (kt + 2) % 3;             // == (kt-1)%3: consumed last iter
    u16* As2 = smem + s2 * 16384;
    u16* Bs2 = smem + 49152 + s2 * 8192;
    const int kof = (kt + 2) * 64;

    // ---------- phase 1: k-step 0 ----------
    short8 a[4], b[4];
#pragma unroll
    for (int i = 0; i < 4; ++i)
      a[i] = *(const short8*)&As[(((wm + i * 16 + r) << 3) + (q ^ xr)) << 3];
#pragma unroll
    for (int j = 0; j < 4; ++j)
      b[j] = *(const short8*)&Bs[(((wn + j * 16 + r) << 3) + (q ^ xr)) << 3];
    if (kt + 2 < NT1) {
      GLD16(a_src[0] + kof, As2 + a_dst[0]);
      GLD16(a_src[1] + kof, As2 + a_dst[1]);
      GLD16(b_src[0] + kof, Bs2 + b_dst[0]);
    }
    __builtin_amdgcn_s_barrier();
    asm volatile("s_waitcnt lgkmcnt(0)" ::: "memory");
    __builtin_amdgcn_sched_barrier(0);          // rule 18: pin MFMA after wait
    __builtin_amdgcn_s_setprio(1);
#pragma unroll
    for (int i = 0; i < 4; ++i)
#pragma unroll
      for (int j = 0; j < 4; ++j)
        acc[i][j] = __builtin_amdgcn_mfma_f32_16x16x32_bf16(a[i], b[j], acc[i][j], 0, 0, 0);
    __builtin_amdgcn_s_setprio(0);
    __builtin_amdgcn_s_barrier();

    // ---------- phase 2: k-step 1 ----------
#pragma unroll
    for (int i = 0; i < 4; ++i)
      a[i] = *(const short8*)&As[(((wm + i * 16 + r) << 3) + ((4 + q) ^ xr)) << 3];
#pragma unroll
    for (int j = 0; j < 4; ++j)
      b[j] = *(const short8*)&Bs[(((wn + j * 16 + r) << 3) + ((4 + q) ^ xr)) << 3];
    if (kt + 2 < NT1) {
      GLD16(a_src[2] + kof, As2 + a_dst[2]);
      GLD16(a_src[3] + kof, As2 + a_dst[3]);
      GLD16(b_src[1] + kof, Bs2 + b_dst[1]);
    }
    __builtin_amdgcn_s_barrier();
    asm volatile("s_waitcnt lgkmcnt(0)" ::: "memory");
    __builtin_amdgcn_sched_barrier(0);          // rule 18
    __builtin_amdgcn_s_setprio(1);
#pragma unroll
    for (int i = 0; i < 4; ++i)
#pragma unroll
      for (int j = 0; j < 4; ++j)
        acc[i][j] = __builtin_amdgcn_mfma_f32_16x16x32_bf16(a[i], b[j], acc[i][j], 0, 0, 0);
    __builtin_amdgcn_s_setprio(0);
    // counted checkpoint: the 6 newest outstanding loads are tile kt+2's ->
    // vmcnt(6) guarantees tile kt+1 is fully in LDS. Only the last two
    // iterations (nothing newer in flight) drain to 0.
    if (kt + 2 < NT1) {
      asm volatile("s_waitcnt vmcnt(6)" ::: "memory");
    } else {
      asm volatile("s_waitcnt vmcnt(0)" ::: "memory");
    }
    __builtin_amdgcn_sched_barrier(0);
    __builtin_amdgcn_s_barrier();
  }

  // ---- epilogue: gelu+bias -> bf16 via LDS, coalesced dwordx4 stores ----
  u16* cs = smem;   // 256 x EPI_STRIDE = 34816 u16, fits in the slot pool
#pragma unroll
  for (int j = 0; j < 4; ++j) {
    const int cl = wn + j * 16 + r;
    const float bn = bias[n0 + cl];
#pragma unroll
    for (int i = 0; i < 4; ++i) {
#pragma unroll
      for (int e = 0; e < 4; ++e) {
        const int rl = wm + i * 16 + q * 4 + e;
        cs[rl * EPI_STRIDE + cl] = f2b(fast_gelu(acc[i][j][e] + bn));
      }
    }
  }
  __syncthreads();
#pragma unroll
  for (int it = 0; it < 8; ++it) {
    const int c = it * 512 + tid;       // 4096 chunks = 256 rows x 16 chunks
    const int rl = c >> 4;              // 0..255
    const int cc = (c & 15) << 3;       // 0..120
    uint4 v = *(const uint4*)&cs[rl * EPI_STRIDE + cc];
    *(uint4*)&H[(long)(m0 + rl) * N + n0 + cc] = v;
  }
}

// ---------------- GEMM2: out = h @ Wrow^T + bias, fp32 out ----------------
// BM=96 (one batch per row-tile), BN=128, BK=64, XOR-swizzled LDS.
// Grid = 128 x 6 = 768 blocks = exactly 3/CU. (unchanged — validated)
__global__ __launch_bounds__(256, 3) void gemm2_kernel(const u16* __restrict__ Hb,
                                                       const u16* __restrict__ W2,
                                                       const u16* __restrict__ WE,
                                                       const float* __restrict__ b2,
                                                       const float* __restrict__ be,
                                                       const int* __restrict__ idx,
                                                       float* __restrict__ Out) {
  constexpr int K = HH;       // 3072
  constexpr int NOUT = DD;    // 768
  __shared__ u16 As[96 * 64];    // 12 KB
  __shared__ u16 Bs[128 * 64];   // 16 KB
  const int tid = threadIdx.x;
  const int lane = tid & 63;
  const int wave = tid >> 6;
  const int m0 = blockIdx.x * 96;
  const int n0 = blockIdx.y * 128;
  const int wm = (wave >> 1) * 48;
  const int wn = (wave & 1) * 64;
  const int q = lane >> 4;
  const int r = lane & 15;
  const int xr = r & 7;

  const u16* Bbase;
  const float* biasp;
  if (n0 < SHARED_N) {
    Bbase = W2 + (long)n0 * K;
    biasp = b2 + n0;
  } else {
    const int e = idx[blockIdx.x >> 1];
    Bbase = WE + ((long)e * PP + (n0 - SHARED_N)) * K;
    biasp = be + e * PP + (n0 - SHARED_N);
  }
  const u16* Abase = Hb + (long)m0 * K;

  floatx4 acc[3][4] = {};

  int a_row[3], a_kcg[3], b_row[4], b_kcg[4];
#pragma unroll
  for (int i = 0; i < 3; ++i) {
    int c = i * 256 + tid;
    a_row[i] = c >> 3;
    a_kcg[i] = (c & 7) ^ (a_row[i] & 7);
  }
#pragma unroll
  for (int i = 0; i < 4; ++i) {
    int c = i * 256 + tid;
    b_row[i] = c >> 3;
    b_kcg[i] = (c & 7) ^ (b_row[i] & 7);
  }

  for (int kt = 0; kt < K / 64; ++kt) {
    const int k0 = kt * 64;
#pragma unroll
    for (int i = 0; i < 3; ++i)
      GLD16(Abase + (long)a_row[i] * K + k0 + a_kcg[i] * 8, &As[(i * 256 + tid) * 8]);
#pragma unroll
    for (int i = 0; i < 4; ++i)
      GLD16(Bbase + (long)b_row[i] * K + k0 + b_kcg[i] * 8, &Bs[(i * 256 + tid) * 8]);
    __syncthreads();

    short8 a[2][3], b[2][4];
#pragma unroll
    for (int ks = 0; ks < 2; ++ks) {
      const int kc = ks * 4 + q;
#pragma unroll
      for (int i = 0; i < 3; ++i)
        a[ks][i] = *(const short8*)&As[(((wm + i * 16 + r) << 3) + (kc ^ xr)) << 3];
#pragma unroll
      for (int j = 0; j < 4; ++j)
        b[ks][j] = *(const short8*)&Bs[(((wn + j * 16 + r) << 3) + (kc ^ xr)) << 3];
    }
#pragma unroll
    for (int ks = 0; ks < 2; ++ks)
#pragma unroll
      for (int i = 0; i < 3; ++i)
#pragma unroll
        for (int j = 0; j < 4; ++j)
          acc[i][j] = __builtin_amdgcn_mfma_f32_16x16x32_bf16(a[ks][i], b[ks][j], acc[i][j], 0, 0, 0);
    __syncthreads();
  }

#pragma unroll
  for (int j = 0; j < 4; ++j) {
    const int cl = wn + j * 16 + r;
    const int col = n0 + cl;
    const float bn = biasp[cl];
#pragma unroll
    for (int i = 0; i < 3; ++i) {
#pragma unroll
      for (int e = 0; e < 4; ++e) {
        const int row = m0 + wm + i * 16 + q * 4 + e;
        Out[(long)row * NOUT + col] = acc[i][j][e] + bn;
      }
    }
  }
}

extern "C" void kernel_launch(void* const* d_in, const int* in_sizes, int n_in,
                              void* d_out, int out_size, void* d_ws, size_t ws_size,
                              hipStream_t stream) {
  const float* x  = (const float*)d_in[0];   // [B,S,D]
  const int*  idx = (const int*)d_in[1];     // [B]
  const float* w1 = (const float*)d_in[2];   // [H,D]
  const float* b1 = (const float*)d_in[3];   // [H]
  const float* w2 = (const float*)d_in[4];   // [SHARED,H]
  const float* b2 = (const float*)d_in[5];   // [SHARED]
  const float* we = (const float*)d_in[6];   // [E,P,H]
  const float* be = (const float*)d_in[7];   // [E,P]
  float* out = (float*)d_out;

  u16* Xb  = (u16*)d_ws;                              // 12288*768
  u16* W1b = Xb  + N_X;                               // 3072*768
  u16* W2b = W1b + N_W1;                              // 512*3072
  u16* WEb = W2b + N_W2;                              // 6*256*3072
  u16* Hb  = WEb + N_WE;                              // 12288*3072

  cvt_all_kernel<<<(int)(N_ALL / 2048), 256, 0, stream>>>(x, w1, w2, we, Xb);
  gemm1_kernel<<<dim3(M_TOT / 256, HH / 128), 512, 0, stream>>>(Xb, W1b, b1, Hb);
  gemm2_kernel<<<dim3(M_TOT / 96, DD / 128), 256, 0, stream>>>(Hb, W2b, WEb, b2, be, idx, out);
}

// Round 4
// 249.513 us; speedup vs baseline: 1.0956x; 1.0956x over previous
//
#include <hip/hip_runtime.h>
#include <hip/hip_bf16.h>

typedef unsigned short u16;
typedef __attribute__((ext_vector_type(8))) short short8;
typedef __attribute__((ext_vector_type(4))) float floatx4;

// ---- problem constants ----
#define BB 64
#define SS 192
#define DD 768
#define HH 3072
#define EE 6
#define PP 256
#define SHARED_N 512
#define M_TOT (BB * SS)          // 12288

#define GLD16(gp, lp) __builtin_amdgcn_global_load_lds(                         \
    (const __attribute__((address_space(1))) unsigned int*)(gp),                \
    (__attribute__((address_space(3))) unsigned int*)(lp), 16, 0, 0)

__device__ __forceinline__ u16 f2b(float x) {
  union { float f; unsigned u; } c; c.f = x;
  return (u16)((c.u + 0x7fffu + ((c.u >> 16) & 1u)) >> 16);  // RTNE
}

// tanh-form GELU via sigmoid identity: 0.5x(1+tanh(z)) == x*sigmoid(2z).
// exp2/rcp are single-inst HW approx. Max abs error vs exact-erf GELU ~3e-4,
// far below bf16 rounding of h (~2e-3) and the 3.9e-2 output threshold.
__device__ __forceinline__ float fast_gelu(float x) {
  const float c = 2.0f * 0.7978845608028654f * 1.4426950408889634f; // 2*sqrt(2/pi)*log2(e)
  float xp = __builtin_fmaf(0.044715f * x * x, x, x);
  float e = __builtin_amdgcn_exp2f(-c * xp);
  return x * __builtin_amdgcn_rcpf(1.0f + e);
}

// -------- fp32 -> bf16 conversion, all 4 operands in ONE launch --------
#define N_X  9437184L   // 12288*768
#define N_W1 2359296L   // 3072*768
#define N_W2 1572864L   // 512*3072
#define N_WE 4718592L   // 6*256*3072
#define N_ALL (N_X + N_W1 + N_W2 + N_WE)  // 18087936

__global__ __launch_bounds__(256) void cvt_all_kernel(const float* __restrict__ x,
                                                      const float* __restrict__ w1,
                                                      const float* __restrict__ w2,
                                                      const float* __restrict__ we,
                                                      u16* __restrict__ dst) {
  long i = ((long)blockIdx.x * blockDim.x + threadIdx.x) * 8;
  const float* src;
  if (i < N_X)                  src = x  + i;
  else if (i < N_X + N_W1)      src = w1 + (i - N_X);
  else if (i < N_X + N_W1 + N_W2) src = w2 + (i - N_X - N_W1);
  else                          src = we + (i - N_X - N_W1 - N_W2);
  float4 a = *(const float4*)(src);
  float4 b = *(const float4*)(src + 4);
  union { u16 us[8]; uint4 v; } r;
  r.us[0] = f2b(a.x); r.us[1] = f2b(a.y); r.us[2] = f2b(a.z); r.us[3] = f2b(a.w);
  r.us[4] = f2b(b.x); r.us[5] = f2b(b.y); r.us[6] = f2b(b.z); r.us[7] = f2b(b.w);
  *(uint4*)(dst + i) = r.v;
}

// ---------------- GEMM1: h = gelu(X @ W1^T + b1), bf16 out ----------------
// 128x128 tile, BK=64, XOR-swizzled LDS (validated R0 structure, 69.2us).
// R4: __launch_bounds__(256,4) — LDS 33.8KB and VGPR ~60 permit 4 blocks/CU;
// more co-resident independent blocks hide each other's barrier drains
// (m114 implicit overlap — the mechanism that beat explicit pipelining here).
#define EPI_STRIDE 132   // 128+4: 264B row stride spreads q-groups across banks
__global__ __launch_bounds__(256, 4) void gemm1_kernel(const u16* __restrict__ X,
                                                       const u16* __restrict__ W,
                                                       const float* __restrict__ bias,
                                                       u16* __restrict__ H) {
  constexpr int K = DD;      // 768
  constexpr int N = HH;      // 3072
  __shared__ u16 smem[128 * EPI_STRIDE];   // 33792 B; K-loop uses first 32 KB
  u16* As = smem;            // 128*64
  u16* Bs = smem + 8192;     // 128*64
  const int tid = threadIdx.x;
  const int lane = tid & 63;
  const int wave = tid >> 6;
  const int m0 = blockIdx.x * 128;
  const int n0 = blockIdx.y * 128;
  const int wm = (wave >> 1) * 64;
  const int wn = (wave & 1) * 64;
  const int q = lane >> 4;
  const int r = lane & 15;
  const int xr = r & 7;

  floatx4 acc[4][4] = {};

  // staging chunk assignments: 128 rows x 8 chunks(16B) = 1024 chunks, 4/thread
  int rowc[4], kcg[4];
#pragma unroll
  for (int i = 0; i < 4; ++i) {
    int c = i * 256 + tid;
    rowc[i] = c >> 3;
    kcg[i] = (c & 7) ^ (rowc[i] & 7);
  }

  for (int kt = 0; kt < K / 64; ++kt) {
    const int k0 = kt * 64;
#pragma unroll
    for (int i = 0; i < 4; ++i)
      GLD16(X + (long)(m0 + rowc[i]) * K + k0 + kcg[i] * 8, &As[(i * 256 + tid) * 8]);
#pragma unroll
    for (int i = 0; i < 4; ++i)
      GLD16(W + (long)(n0 + rowc[i]) * K + k0 + kcg[i] * 8, &Bs[(i * 256 + tid) * 8]);
    __syncthreads();

#pragma unroll
    for (int ks = 0; ks < 2; ++ks) {
      const int kc = ks * 4 + q;
      short8 a[4], b[4];
#pragma unroll
      for (int i = 0; i < 4; ++i)
        a[i] = *(const short8*)&As[(((wm + i * 16 + r) << 3) + (kc ^ xr)) << 3];
#pragma unroll
      for (int j = 0; j < 4; ++j)
        b[j] = *(const short8*)&Bs[(((wn + j * 16 + r) << 3) + (kc ^ xr)) << 3];
#pragma unroll
      for (int i = 0; i < 4; ++i)
#pragma unroll
        for (int j = 0; j < 4; ++j)
          acc[i][j] = __builtin_amdgcn_mfma_f32_16x16x32_bf16(a[i], b[j], acc[i][j], 0, 0, 0);
    }
    __syncthreads();
  }
  // last loop barrier guarantees all frag reads done -> smem reusable

#pragma unroll
  for (int j = 0; j < 4; ++j) {
    const int cl = wn + j * 16 + r;
    const float bn = bias[n0 + cl];
#pragma unroll
    for (int i = 0; i < 4; ++i) {
#pragma unroll
      for (int e = 0; e < 4; ++e) {
        const int rl = wm + i * 16 + q * 4 + e;
        smem[rl * EPI_STRIDE + cl] = f2b(fast_gelu(acc[i][j][e] + bn));
      }
    }
  }
  __syncthreads();

  const int er = tid >> 4;            // 0..15
  const int ec = (tid & 15) * 8;      // 0..120
#pragma unroll
  for (int it = 0; it < 8; ++it) {
    const int rl = er + it * 16;
    uint4 v = *(const uint4*)&smem[rl * EPI_STRIDE + ec];
    *(uint4*)&H[(long)(m0 + rl) * N + n0 + ec] = v;
  }
}

// ---------------- GEMM2: out = h @ Wrow^T + bias, fp32 out ----------------
// BM=96 (one batch per row-tile), BN=128, BK=64, XOR-swizzled LDS.
// Grid = 128 x 6 = 768 blocks = exactly 3/CU.
// R4: __launch_bounds__(256,4) — same occupancy-headroom reasoning as gemm1.
__global__ __launch_bounds__(256, 4) void gemm2_kernel(const u16* __restrict__ Hb,
                                                       const u16* __restrict__ W2,
                                                       const u16* __restrict__ WE,
                                                       const float* __restrict__ b2,
                                                       const float* __restrict__ be,
                                                       const int* __restrict__ idx,
                                                       float* __restrict__ Out) {
  constexpr int K = HH;       // 3072
  constexpr int NOUT = DD;    // 768
  __shared__ u16 As[96 * 64];    // 12 KB
  __shared__ u16 Bs[128 * 64];   // 16 KB
  const int tid = threadIdx.x;
  const int lane = tid & 63;
  const int wave = tid >> 6;
  const int m0 = blockIdx.x * 96;
  const int n0 = blockIdx.y * 128;
  const int wm = (wave >> 1) * 48;
  const int wn = (wave & 1) * 64;
  const int q = lane >> 4;
  const int r = lane & 15;
  const int xr = r & 7;

  const u16* Bbase;
  const float* biasp;
  if (n0 < SHARED_N) {
    Bbase = W2 + (long)n0 * K;
    biasp = b2 + n0;
  } else {
    const int e = idx[blockIdx.x >> 1];
    Bbase = WE + ((long)e * PP + (n0 - SHARED_N)) * K;
    biasp = be + e * PP + (n0 - SHARED_N);
  }
  const u16* Abase = Hb + (long)m0 * K;

  floatx4 acc[3][4] = {};

  int a_row[3], a_kcg[3], b_row[4], b_kcg[4];
#pragma unroll
  for (int i = 0; i < 3; ++i) {
    int c = i * 256 + tid;
    a_row[i] = c >> 3;
    a_kcg[i] = (c & 7) ^ (a_row[i] & 7);
  }
#pragma unroll
  for (int i = 0; i < 4; ++i) {
    int c = i * 256 + tid;
    b_row[i] = c >> 3;
    b_kcg[i] = (c & 7) ^ (b_row[i] & 7);
  }

  for (int kt = 0; kt < K / 64; ++kt) {
    const int k0 = kt * 64;
#pragma unroll
    for (int i = 0; i < 3; ++i)
      GLD16(Abase + (long)a_row[i] * K + k0 + a_kcg[i] * 8, &As[(i * 256 + tid) * 8]);
#pragma unroll
    for (int i = 0; i < 4; ++i)
      GLD16(Bbase + (long)b_row[i] * K + k0 + b_kcg[i] * 8, &Bs[(i * 256 + tid) * 8]);
    __syncthreads();

    short8 a[2][3], b[2][4];
#pragma unroll
    for (int ks = 0; ks < 2; ++ks) {
      const int kc = ks * 4 + q;
#pragma unroll
      for (int i = 0; i < 3; ++i)
        a[ks][i] = *(const short8*)&As[(((wm + i * 16 + r) << 3) + (kc ^ xr)) << 3];
#pragma unroll
      for (int j = 0; j < 4; ++j)
        b[ks][j] = *(const short8*)&Bs[(((wn + j * 16 + r) << 3) + (kc ^ xr)) << 3];
    }
#pragma unroll
    for (int ks = 0; ks < 2; ++ks)
#pragma unroll
      for (int i = 0; i < 3; ++i)
#pragma unroll
        for (int j = 0; j < 4; ++j)
          acc[i][j] = __builtin_amdgcn_mfma_f32_16x16x32_bf16(a[ks][i], b[ks][j], acc[i][j], 0, 0, 0);
    __syncthreads();
  }

#pragma unroll
  for (int j = 0; j < 4; ++j) {
    const int cl = wn + j * 16 + r;
    const int col = n0 + cl;
    const float bn = biasp[cl];
#pragma unroll
    for (int i = 0; i < 3; ++i) {
#pragma unroll
      for (int e = 0; e < 4; ++e) {
        const int row = m0 + wm + i * 16 + q * 4 + e;
        Out[(long)row * NOUT + col] = acc[i][j][e] + bn;
      }
    }
  }
}

extern "C" void kernel_launch(void* const* d_in, const int* in_sizes, int n_in,
                              void* d_out, int out_size, void* d_ws, size_t ws_size,
                              hipStream_t stream) {
  const float* x  = (const float*)d_in[0];   // [B,S,D]
  const int*  idx = (const int*)d_in[1];     // [B]
  const float* w1 = (const float*)d_in[2];   // [H,D]
  const float* b1 = (const float*)d_in[3];   // [H]
  const float* w2 = (const float*)d_in[4];   // [SHARED,H]
  const float* b2 = (const float*)d_in[5];   // [SHARED]
  const float* we = (const float*)d_in[6];   // [E,P,H]
  const float* be = (const float*)d_in[7];   // [E,P]
  float* out = (float*)d_out;

  u16* Xb  = (u16*)d_ws;                              // 12288*768
  u16* W1b = Xb  + N_X;                               // 3072*768
  u16* W2b = W1b + N_W1;                              // 512*3072
  u16* WEb = W2b + N_W2;                              // 6*256*3072
  u16* Hb  = WEb + N_WE;                              // 12288*3072

  cvt_all_kernel<<<(int)(N_ALL / 2048), 256, 0, stream>>>(x, w1, w2, we, Xb);
  gemm1_kernel<<<dim3(M_TOT / 128, HH / 128), 256, 0, stream>>>(Xb, W1b, b1, Hb);
  gemm2_kernel<<<dim3(M_TOT / 96, DD / 128), 256, 0, stream>>>(Hb, W2b, WEb, b2, be, idx, out);
}